// Round 9
// baseline (780.002 us; speedup 1.0000x reference)
//
#include <hip/hip_runtime.h>

// z = conv3x3(x, w) (pad 1, cross-correlation, NCHW/OIHW); LIF scan over t:
//   v = v + (z - v)*0.5 ; s = (v >= 1) ; v = s ? 0 : v
// NUMERICS INVARIANT (verified bit-exact R5/R6): per output element the conv
// is a SINGLE sequential f32 FMA chain over k = (tap, ci), tap = ky*3+kx
// outer, ci INNERMOST (Eigen/XLA-CPU order), acc starts at 0; padding taps are
// exact fma no-ops (zero halo). LIF ops separately rounded; *0.5 exact.
// R16 = R15 resubmitted (R15 bench was a container-acquire failure, no data).
// R15: R14 retry with the register budget fixed. R14's VGPR_Count=60 proved
// the 64-float accumulator spilled (launch_bounds without min-waves let the
// compiler target high occupancy). Occupancy is LDS-pinned at 2 waves/SIMD
// anyway (153 KB dynamic LDS, 1 block/CU), so __launch_bounds__(512, 2)
// raises the budget to 256 VGPR -> no spill (~100 needed). Everything else
// identical to R14. Decision gate: VGPR>=96 & conv<483 else revert to R13.

namespace {
constexpr int T = 16, N = 8, C = 64, H = 64, W = 64;
constexpr int HW   = H * W;       // 4096
constexpr int CHW  = C * HW;      // 262144
constexpr int NCHW = N * CHW;     // 2097152
constexpr int NWT  = C * C * 9;   // 36864
// R13 fallback conv geometry:
constexpr int NPOS = 10 * 18;     // 180 halo positions (8x16 tile)
// Big-tile conv geometry:
constexpr int BPOS = 18 * 34;     // 612 halo positions (16x32 tile)
constexpr int BLDS = 16 * BPOS * 16;  // 156672 bytes
}

// Transpose weights (O,I,3,3) -> wt2[tap][ci][cout]: per (tap,ci) couts are
// contiguous -> wave-uniform s_load of 16 floats per wave per (tap,ci).
__global__ void wtr_kernel(const float* __restrict__ w, float* __restrict__ wt2) {
    int i = blockIdx.x * 256 + threadIdx.x;     // i = (cout*64 + ci)*9 + tap
    if (i >= NWT) return;
    int tap  = i % 9;
    int rem  = i / 9;
    int ci   = rem % 64;
    int cout = rem / 64;
    wt2[(tap * 64 + ci) * 64 + cout] = w[i];
}

// Big conv: block = 512 threads = 8 waves = one (t, n, 16x32 tile), 64 couts.
// Wave w: couts [16*(w&3), +16); row-half (w>>2): rows [8*(w>>2), +8).
// Lane: py = lane>>3 (row in half), px = lane&7; 4 pixels: cols px+{0,8,16,24}.
// LDS float4-granule layout: granule = cib*BPOS + pos, pos = dy*34+dx;
// element (pos,ci) at float slot (ci>>2)*(BPOS*4) + pos*4 + (ci&3).
__global__ __launch_bounds__(512, 2) void conv_big(
    const float* __restrict__ x,
    const float* __restrict__ wt2,
    float*       __restrict__ zo)
{
#pragma clang fp contract(off)
    extern __shared__ float xs[];      // 156672 B

    const int tid  = threadIdx.x;
    const int wave = __builtin_amdgcn_readfirstlane(tid >> 6);
    const int lane = tid & 63;
    const int px = lane & 7;
    const int py = lane >> 3;
    const int c0  = (wave & 3) << 4;   // 16 couts per wave
    const int row = ((wave >> 2) << 3) + py;   // 0..15 within tile

    const int bid  = blockIdx.x;       // 1024 = 16 t * 8 n * 8 tiles
    const int t    = bid >> 6;
    const int r    = bid & 63;
    const int n    = r >> 3;
    const int tile = r & 7;
    const int th0 = (tile >> 1) << 4;  // 4 row-tiles (16 rows)
    const int tw0 = (tile & 1) << 5;   // 2 col-tiles (32 cols)

    const float* xt = x + (size_t)(t * N + n) * CHW;

    // Stage x[t][n][ci][th0-1..+16][tw0-1..+32] transposed into LDS (zero halo).
#pragma unroll
    for (int it = 0; it < 77; ++it) {
        int j = tid + it * 512;
        if (j < 64 * BPOS) {
            int ci = j / BPOS;
            int rr = j - ci * BPOS;
            int dy = rr / 34;
            int dx = rr - dy * 34;
            int hh = th0 - 1 + dy;
            int ww = tw0 - 1 + dx;
            float val = 0.0f;
            if ((unsigned)hh < (unsigned)H && (unsigned)ww < (unsigned)W)
                val = xt[ci * HW + hh * W + ww];
            xs[(ci >> 2) * (BPOS * 4) + rr * 4 + (ci & 3)] = val;
        }
    }
    __syncthreads();

    float acc0[16], acc1[16], acc2[16], acc3[16];
#pragma unroll
    for (int i = 0; i < 16; ++i) {
        acc0[i] = 0.0f; acc1[i] = 0.0f; acc2[i] = 0.0f; acc3[i] = 0.0f;
    }

    // Chain per acc[cc]: tap outer (9), ci 0..63 ascending inner; one fmaf
    // per k; only load scheduling varies, never FMA order. The 4 pixels'
    // chains are independent and identically ordered.
    for (int tap = 0; tap < 9; ++tap) {
        const int ky = tap / 3, kx = tap - 3 * ky;
        const int pos = (row + ky) * 34 + (px + kx);  // cols: +0,+8,+16,+24
        const float4* xp = (const float4*)xs + pos;   // + cib*BPOS granules
        const float* wtap = wt2 + tap * 4096 + c0;    // wave-uniform
#pragma unroll 2
        for (int cib = 0; cib < 16; ++cib) {
            const float4 xv0 = xp[cib * BPOS];
            const float4 xv1 = xp[cib * BPOS + 8];
            const float4 xv2 = xp[cib * BPOS + 16];
            const float4 xv3 = xp[cib * BPOS + 24];
            const float* wp = wtap + cib * 256;       // (tap, ci=4*cib) block
#pragma unroll
            for (int cc = 0; cc < 16; ++cc) {
                float w0 = wp[cc];
                acc0[cc] = fmaf(w0, xv0.x, acc0[cc]);
                acc1[cc] = fmaf(w0, xv1.x, acc1[cc]);
                acc2[cc] = fmaf(w0, xv2.x, acc2[cc]);
                acc3[cc] = fmaf(w0, xv3.x, acc3[cc]);
            }
#pragma unroll
            for (int cc = 0; cc < 16; ++cc) {
                float w1 = wp[64 + cc];
                acc0[cc] = fmaf(w1, xv0.y, acc0[cc]);
                acc1[cc] = fmaf(w1, xv1.y, acc1[cc]);
                acc2[cc] = fmaf(w1, xv2.y, acc2[cc]);
                acc3[cc] = fmaf(w1, xv3.y, acc3[cc]);
            }
#pragma unroll
            for (int cc = 0; cc < 16; ++cc) {
                float w2 = wp[128 + cc];
                acc0[cc] = fmaf(w2, xv0.z, acc0[cc]);
                acc1[cc] = fmaf(w2, xv1.z, acc1[cc]);
                acc2[cc] = fmaf(w2, xv2.z, acc2[cc]);
                acc3[cc] = fmaf(w2, xv3.z, acc3[cc]);
            }
#pragma unroll
            for (int cc = 0; cc < 16; ++cc) {
                float w3 = wp[192 + cc];
                acc0[cc] = fmaf(w3, xv0.w, acc0[cc]);
                acc1[cc] = fmaf(w3, xv1.w, acc1[cc]);
                acc2[cc] = fmaf(w3, xv2.w, acc2[cc]);
                acc3[cc] = fmaf(w3, xv3.w, acc3[cc]);
            }
        }
    }

    float* zt = zo + (size_t)(t * N + n) * CHW;
    const int pbase = (th0 + row) * W + (tw0 + px);
#pragma unroll
    for (int cc = 0; cc < 16; ++cc) {
        zt[(c0 + cc) * HW + pbase]      = acc0[cc];
        zt[(c0 + cc) * HW + pbase + 8]  = acc1[cc];
        zt[(c0 + cc) * HW + pbase + 16] = acc2[cc];
        zt[(c0 + cc) * HW + pbase + 24] = acc3[cc];
    }
}

// R13 fallback conv (proven 483us): 256 threads, 8x16 tile, 2 px/lane.
__global__ __launch_bounds__(256, 3) void conv_kernel(
    const float* __restrict__ x,
    const float* __restrict__ wt2,
    float*       __restrict__ zo)
{
#pragma clang fp contract(off)
    __shared__ float xs[16 * NPOS * 4];   // 46.08KB

    const int tid  = threadIdx.x;
    const int wave = __builtin_amdgcn_readfirstlane(tid >> 6);
    const int lane = tid & 63;
    const int px = lane & 7;
    const int py = lane >> 3;
    const int c0 = wave << 4;

    const int bid  = blockIdx.x;       // 4096 = 16 t * 8 n * 32 tiles
    const int t    = bid >> 8;
    const int r    = bid & 255;
    const int n    = r >> 5;
    const int tile = r & 31;
    const int th0 = (tile >> 2) << 3;
    const int tw0 = (tile & 3) << 4;

    const float* xt = x + (size_t)(t * N + n) * CHW;

#pragma unroll
    for (int it = 0; it < 45; ++it) {
        int j  = tid + it * 256;
        int ci = j / NPOS;
        int rr = j - ci * NPOS;
        int dy = rr / 18;
        int dx = rr - dy * 18;
        int hh = th0 - 1 + dy;
        int ww = tw0 - 1 + dx;
        float val = 0.0f;
        if ((unsigned)hh < (unsigned)H && (unsigned)ww < (unsigned)W)
            val = xt[ci * HW + hh * W + ww];
        xs[(ci >> 2) * (NPOS * 4) + rr * 4 + (ci & 3)] = val;
    }
    __syncthreads();

    float acc0[16], acc1[16];
#pragma unroll
    for (int i = 0; i < 16; ++i) { acc0[i] = 0.0f; acc1[i] = 0.0f; }

    for (int tap = 0; tap < 9; ++tap) {
        const int ky = tap / 3, kx = tap - 3 * ky;
        const int pos = (py + ky) * 18 + (px + kx);
        const float4* xp = (const float4*)xs + pos;
        const float* wtap = wt2 + tap * 4096 + c0;
#pragma unroll 2
        for (int cib = 0; cib < 16; ++cib) {
            const float4 xv0 = xp[cib * NPOS];
            const float4 xv1 = xp[cib * NPOS + 8];
            const float* wp = wtap + cib * 256;
#pragma unroll
            for (int cc = 0; cc < 16; ++cc) {
                float w0 = wp[cc];
                acc0[cc] = fmaf(w0, xv0.x, acc0[cc]);
                acc1[cc] = fmaf(w0, xv1.x, acc1[cc]);
            }
#pragma unroll
            for (int cc = 0; cc < 16; ++cc) {
                float w1 = wp[64 + cc];
                acc0[cc] = fmaf(w1, xv0.y, acc0[cc]);
                acc1[cc] = fmaf(w1, xv1.y, acc1[cc]);
            }
#pragma unroll
            for (int cc = 0; cc < 16; ++cc) {
                float w2 = wp[128 + cc];
                acc0[cc] = fmaf(w2, xv0.z, acc0[cc]);
                acc1[cc] = fmaf(w2, xv1.z, acc1[cc]);
            }
#pragma unroll
            for (int cc = 0; cc < 16; ++cc) {
                float w3 = wp[192 + cc];
                acc0[cc] = fmaf(w3, xv0.w, acc0[cc]);
                acc1[cc] = fmaf(w3, xv1.w, acc1[cc]);
            }
        }
    }

    float* zt = zo + (size_t)(t * N + n) * CHW;
    const int pbase = (th0 + py) * W + (tw0 + px);
#pragma unroll
    for (int cc = 0; cc < 16; ++cc) {
        zt[(c0 + cc) * HW + pbase]     = acc0[cc];
        zt[(c0 + cc) * HW + pbase + 8] = acc1[cc];
    }
}

// LIF scan, in-place on zo (reads z, writes 0/1 spikes). One thread per FOUR
// consecutive (n,c,h,w) neurons (float4); t-loop carries v in registers.
// Elementwise ops separately rounded, identical per-element order.
__global__ void lif_kernel(float* __restrict__ zo) {
#pragma clang fp contract(off)
    const int gid = blockIdx.x * 256 + threadIdx.x;   // [0, NCHW/4)
    float4 v;
    v.x = 0.0f; v.y = 0.0f; v.z = 0.0f; v.w = 0.0f;
#pragma unroll
    for (int t = 0; t < T; ++t) {
        float4* p = (float4*)(zo + (size_t)t * NCHW) + gid;
        float4 z = *p;
        float4 s;
#define LIF_STEP(comp) { float d = z.comp - v.comp; float hh = d * 0.5f;      \
        v.comp = v.comp + hh;                                                  \
        if (v.comp >= 1.0f) { s.comp = 1.0f; v.comp = 0.0f; }                  \
        else                { s.comp = 0.0f; } }
        LIF_STEP(x) LIF_STEP(y) LIF_STEP(z) LIF_STEP(w)
#undef LIF_STEP
        *p = s;
    }
}

extern "C" void kernel_launch(void* const* d_in, const int* in_sizes, int n_in,
                              void* d_out, int out_size, void* d_ws, size_t ws_size,
                              hipStream_t stream) {
    const float* x = (const float*)d_in[0];
    const float* w = (const float*)d_in[1];
    if (n_in >= 2 && in_sizes[0] < in_sizes[1]) {   // defensive: pick by size
        const float* tmp = x; x = w; w = tmp;
    }
    float* out = (float*)d_out;
    float* wt2 = (float*)d_ws;                       // 36864 floats = 144 KB

    static int big_ok = -1;
    if (big_ok < 0) {
        hipError_t e = hipFuncSetAttribute(
            reinterpret_cast<const void*>(&conv_big),
            hipFuncAttributeMaxDynamicSharedMemorySize, BLDS);
        big_ok = (e == hipSuccess) ? 1 : 0;
        (void)hipGetLastError();                     // clear any error state
    }

    wtr_kernel<<<(NWT + 255) / 256, 256, 0, stream>>>(w, wt2);
    if (big_ok)
        conv_big<<<T * N * 8, 512, BLDS, stream>>>(x, wt2, out);
    else
        conv_kernel<<<T * N * 32, 256, 0, stream>>>(x, wt2, out);
    lif_kernel<<<NCHW / 1024, 256, 0, stream>>>(out);
}

// Round 10
// 627.421 us; speedup vs baseline: 1.2432x; 1.2432x over previous
//
#include <hip/hip_runtime.h>

// z = conv3x3(x, w) (pad 1, cross-correlation, NCHW/OIHW); LIF scan over t:
//   v = v + (z - v)*0.5 ; s = (v >= 1) ; v = s ? 0 : v
// NUMERICS INVARIANT (verified bit-exact R5/R6): per output element the conv
// is a SINGLE sequential f32 FMA chain over k = (tap, ci), tap = ky*3+kx
// outer, ci INNERMOST (Eigen/XLA-CPU order), acc starts at 0; padding taps are
// exact fma no-ops (zero halo). LIF ops separately rounded; *0.5 exact.
// R17: FINAL revert to R13 (best measured: 632us total, conv 483us).
// Closed axes (all measured): occupancy >3 waves/SIMD (R10: null), LDS
// swizzles (R8/R10/R11: conflicts inherent ~8.9/ds_read_b128, layout-
// invariant), cib unroll 4 (R12: -35us), conv+LIF fusion (R9: 3x regression,
// staging serialization), 4px/lane big-tile 153KB dynamic LDS (R14/R16:
// +30%; NOT a spill — acc lives in AGPRs, VALU time unchanged; pure TLP
// starvation at 2 waves/SIMD; per-wave ILP does not substitute for TLP).
// Remaining gap (conv 483 vs 246 FMA floor) is the compiler's per-cib
// lgkm-drain schedule — needs inline-asm pipelining, out of scope.

namespace {
constexpr int T = 16, N = 8, C = 64, H = 64, W = 64;
constexpr int HW   = H * W;       // 4096
constexpr int CHW  = C * HW;      // 262144
constexpr int NCHW = N * CHW;     // 2097152
constexpr int NWT  = C * C * 9;   // 36864
constexpr int NPOS = 10 * 18;     // 180 halo positions (8x16 tile)
}

// Transpose weights (O,I,3,3) -> wt2[tap][ci][cout]: per (tap,ci) couts are
// contiguous -> wave-uniform s_load of 16 floats per wave per (tap,ci).
__global__ void wtr_kernel(const float* __restrict__ w, float* __restrict__ wt2) {
    int i = blockIdx.x * 256 + threadIdx.x;     // i = (cout*64 + ci)*9 + tap
    if (i >= NWT) return;
    int tap  = i % 9;
    int rem  = i / 9;
    int ci   = rem % 64;
    int cout = rem / 64;
    wt2[(tap * 64 + ci) * 64 + cout] = w[i];
}

// Conv only. Block: 256 threads = 4 waves = one (t, n, 8x16 tile), 64 couts.
// Wave w: 64 lanes cover all 128 pixels (2 per lane: px, px+8); couts
// [16w, 16w+16). LDS float4-granule layout: granule = cib*NPOS + pos,
// pos = dy*18+dx; element (pos,ci) at float slot (ci>>2)*720 + pos*4 + (ci&3).
__global__ __launch_bounds__(256, 3) void conv_kernel(
    const float* __restrict__ x,
    const float* __restrict__ wt2,
    float*       __restrict__ zo)
{
#pragma clang fp contract(off)
    __shared__ float xs[16 * NPOS * 4];   // 16 ci-granules x 180 pos x 16B = 46.08KB

    const int tid  = threadIdx.x;
    const int wave = __builtin_amdgcn_readfirstlane(tid >> 6);
    const int lane = tid & 63;
    const int px = lane & 7;           // second pixel at px+8
    const int py = lane >> 3;
    const int c0 = wave << 4;          // 16 couts per wave

    const int bid  = blockIdx.x;       // 4096 = 16 t * 8 n * 32 tiles
    const int t    = bid >> 8;
    const int r    = bid & 255;
    const int n    = r >> 5;
    const int tile = r & 31;
    const int th0 = (tile >> 2) << 3;  // 8 row-tiles
    const int tw0 = (tile & 3) << 4;   // 4 col-tiles (16 wide)

    const float* xt = x + (size_t)(t * N + n) * CHW;

    // Stage x[t][n][ci][th0-1..+8][tw0-1..+16] transposed into LDS (zero halo).
#pragma unroll
    for (int it = 0; it < 45; ++it) {              // 11520 = 45 * 256
        int j  = tid + it * 256;
        int ci = j / NPOS;
        int rr = j - ci * NPOS;
        int dy = rr / 18;
        int dx = rr - dy * 18;
        int hh = th0 - 1 + dy;
        int ww = tw0 - 1 + dx;
        float val = 0.0f;
        if ((unsigned)hh < (unsigned)H && (unsigned)ww < (unsigned)W)
            val = xt[ci * HW + hh * W + ww];
        xs[(ci >> 2) * (NPOS * 4) + rr * 4 + (ci & 3)] = val;
    }
    __syncthreads();

    float acc0[16], acc1[16];
#pragma unroll
    for (int i = 0; i < 16; ++i) { acc0[i] = 0.0f; acc1[i] = 0.0f; }

    // Chain per acc[cc]: tap outer (9), ci 0..63 ascending inner; one fmaf
    // per k; only load scheduling varies, never FMA order. Both pixels'
    // chains are independent and identically ordered.
    for (int tap = 0; tap < 9; ++tap) {
        const int ky = tap / 3, kx = tap - 3 * ky;
        const int pos = (py + ky) * 18 + (px + kx);   // second pixel: pos + 8
        const float4* xp = (const float4*)xs + pos;   // + cib*NPOS granules
        const float* wtap = wt2 + tap * 4096 + c0;    // wave-uniform
#pragma unroll 2
        for (int cib = 0; cib < 16; ++cib) {
            const float4 xv0 = xp[cib * NPOS];
            const float4 xv1 = xp[cib * NPOS + 8];
            const float* wp = wtap + cib * 256;       // (tap, ci=4*cib) block
#pragma unroll
            for (int cc = 0; cc < 16; ++cc) {
                float w0 = wp[cc];
                acc0[cc] = fmaf(w0, xv0.x, acc0[cc]);
                acc1[cc] = fmaf(w0, xv1.x, acc1[cc]);
            }
#pragma unroll
            for (int cc = 0; cc < 16; ++cc) {
                float w1 = wp[64 + cc];
                acc0[cc] = fmaf(w1, xv0.y, acc0[cc]);
                acc1[cc] = fmaf(w1, xv1.y, acc1[cc]);
            }
#pragma unroll
            for (int cc = 0; cc < 16; ++cc) {
                float w2 = wp[128 + cc];
                acc0[cc] = fmaf(w2, xv0.z, acc0[cc]);
                acc1[cc] = fmaf(w2, xv1.z, acc1[cc]);
            }
#pragma unroll
            for (int cc = 0; cc < 16; ++cc) {
                float w3 = wp[192 + cc];
                acc0[cc] = fmaf(w3, xv0.w, acc0[cc]);
                acc1[cc] = fmaf(w3, xv1.w, acc1[cc]);
            }
        }
    }

    float* zt = zo + (size_t)(t * N + n) * CHW;
    const int pbase = (th0 + py) * W + (tw0 + px);
#pragma unroll
    for (int cc = 0; cc < 16; ++cc) {
        zt[(c0 + cc) * HW + pbase]     = acc0[cc];
        zt[(c0 + cc) * HW + pbase + 8] = acc1[cc];
    }
}

// LIF scan, in-place on zo (reads z, writes 0/1 spikes). One thread per FOUR
// consecutive (n,c,h,w) neurons (float4); t-loop carries v in registers.
// Elementwise ops separately rounded, identical per-element order.
__global__ void lif_kernel(float* __restrict__ zo) {
#pragma clang fp contract(off)
    const int gid = blockIdx.x * 256 + threadIdx.x;   // [0, NCHW/4)
    float4 v;
    v.x = 0.0f; v.y = 0.0f; v.z = 0.0f; v.w = 0.0f;
#pragma unroll
    for (int t = 0; t < T; ++t) {
        float4* p = (float4*)(zo + (size_t)t * NCHW) + gid;
        float4 z = *p;
        float4 s;
#define LIF_STEP(comp) { float d = z.comp - v.comp; float hh = d * 0.5f;      \
        v.comp = v.comp + hh;                                                  \
        if (v.comp >= 1.0f) { s.comp = 1.0f; v.comp = 0.0f; }                  \
        else                { s.comp = 0.0f; } }
        LIF_STEP(x) LIF_STEP(y) LIF_STEP(z) LIF_STEP(w)
#undef LIF_STEP
        *p = s;
    }
}

extern "C" void kernel_launch(void* const* d_in, const int* in_sizes, int n_in,
                              void* d_out, int out_size, void* d_ws, size_t ws_size,
                              hipStream_t stream) {
    const float* x = (const float*)d_in[0];
    const float* w = (const float*)d_in[1];
    if (n_in >= 2 && in_sizes[0] < in_sizes[1]) {   // defensive: pick by size
        const float* tmp = x; x = w; w = tmp;
    }
    float* out = (float*)d_out;
    float* wt2 = (float*)d_ws;                       // 36864 floats = 144 KB

    wtr_kernel<<<(NWT + 255) / 256, 256, 0, stream>>>(w, wt2);
    conv_kernel<<<T * N * 32, 256, 0, stream>>>(x, wt2, out);
    lif_kernel<<<NCHW / 1024, 256, 0, stream>>>(out);
}